// Round 11
// baseline (1565.488 us; speedup 1.0000x reference)
//
#include <hip/hip_runtime.h>

// GCN user tower: user_h = relu(D^-1/2 (A+I) D^-1/2 @ W + b), items passthrough.
// v3: bucket-partition (500 buckets x 200 rows) -> packed 4B pairs with
// sequential write heads (merges in L2, kills the 196MB RMW of v2's bin) ->
// fused LDS-accumulate kernel (ds_add_f32) replacing perm+CSR+gather.
// All scratch lives in the dead item half of d_out (13.7 MB < 25.6 MB).

constexpr int N_USERS = 100000;
constexpr int EMB = 64;
constexpr int RPB = 200;                     // rows per bucket
constexpr int NB = (N_USERS + RPB - 1) / RPB; // 500 buckets
constexpr int PAD = 16;                      // u32 stride = 64 B, one line per counter

// --- 1. fused degree histogram + bucket histogram (int atomics, L2-resident) ---
__global__ void count_hist_kernel(const int* __restrict__ row, int E,
                                  unsigned* __restrict__ deg,
                                  unsigned* __restrict__ hist /*padded*/) {
    int stride = gridDim.x * blockDim.x;
    for (int e = blockIdx.x * blockDim.x + threadIdx.x; e < E; e += stride) {
        int r = row[e];
        atomicAdd(&deg[r], 1u);
        atomicAdd(&hist[(r / RPB) * PAD], 1u);
    }
}

// --- 2. deg_inv_sqrt (self loop folded: deg+1) ---
__global__ void dis_kernel(const unsigned* __restrict__ deg,
                           float* __restrict__ dis, int n) {
    int i = blockIdx.x * blockDim.x + threadIdx.x;
    if (i < n) dis[i] = rsqrtf((float)(deg[i] + 1u));
}

// --- 3. exclusive scan of 500 bucket counts (single block) ---
__global__ void scan_hist_kernel(const unsigned* __restrict__ hist,
                                 unsigned* __restrict__ base,
                                 unsigned* __restrict__ cursor, int nb) {
    __shared__ unsigned tmp[512];
    int t = threadIdx.x;
    unsigned v = (t < nb) ? hist[t * PAD] : 0u;
    tmp[t] = v;
    __syncthreads();
    for (int off = 1; off < 512; off <<= 1) {
        unsigned add = (t >= off) ? tmp[t - off] : 0u;
        __syncthreads();
        tmp[t] += add;
        __syncthreads();
    }
    if (t < nb) {
        unsigned excl = tmp[t] - v;
        base[t] = excl;
        cursor[t * PAD] = excl;
    }
    if (t == nb) base[nb] = tmp[nb - 1];  // total = E
}

// --- 4. scatter packed pairs into bucket regions (sequential write heads) ---
__global__ void scatter_pairs_kernel(const int* __restrict__ row,
                                     const int* __restrict__ col,
                                     unsigned* __restrict__ cursor /*padded*/,
                                     unsigned* __restrict__ pairs, int E) {
    int stride = gridDim.x * blockDim.x;
    for (int e = blockIdx.x * blockDim.x + threadIdx.x; e < E; e += stride) {
        int r = row[e];
        int c = col[e];
        int b = r / RPB;                       // magic-mul const divide
        unsigned pos = atomicAdd(&cursor[b * PAD], 1u);
        pairs[pos] = ((unsigned)(r - b * RPB) << 17) | (unsigned)c;  // 8+17 bits
    }
}

// --- 5. fused aggregate: LDS accumulator per bucket + self loop + bias + relu ---
__global__ __launch_bounds__(512) void aggregate_kernel(
    const unsigned* __restrict__ base,
    const float* __restrict__ dis,
    const unsigned* __restrict__ pairs,
    const float4* __restrict__ uw4,
    const float4* __restrict__ bias4,
    float4* __restrict__ out4) {
    __shared__ float acc[RPB * EMB];   // 51200 B
    __shared__ float disr[RPB];
    const int b = blockIdx.x;
    const int tid = threadIdx.x;

    // zero accumulator, cache this bucket's dis
    float4* acc4 = (float4*)acc;
    for (int i = tid; i < RPB * EMB / 4; i += 512)
        acc4[i] = make_float4(0.f, 0.f, 0.f, 0.f);
    for (int i = tid; i < RPB; i += 512)
        disr[i] = dis[b * RPB + i];
    __syncthreads();

    const unsigned s = base[b], e = base[b + 1];
    const int g = tid >> 4;   // 32 groups of 16 lanes per block
    const int l = tid & 15;
    for (unsigned k = s + g; k < e; k += 32) {
        unsigned p = pairs[k];
        unsigned rl = p >> 17;
        unsigned c = p & 0x1FFFFu;
        float norm = disr[rl] * dis[c];
        float4 w = uw4[(size_t)c * 16 + l];
        float* dst = &acc[rl * EMB + l * 4];
        atomicAdd(dst + 0, w.x * norm);
        atomicAdd(dst + 1, w.y * norm);
        atomicAdd(dst + 2, w.z * norm);
        atomicAdd(dst + 3, w.w * norm);
    }
    __syncthreads();

    // self loop + bias + relu + coalesced writeout
    for (int i = tid; i < RPB * (EMB / 4); i += 512) {
        int rl = i >> 4;
        int l4 = i & 15;
        int r = b * RPB + rl;
        float d = disr[rl];
        float inv = d * d;  // 1/deg_total
        float4 w = uw4[(size_t)r * 16 + l4];
        float4 bb = bias4[l4];
        float4 a = acc4[i];
        float4 o;
        o.x = fmaxf(fmaf(w.x, inv, a.x) + bb.x, 0.f);
        o.y = fmaxf(fmaf(w.y, inv, a.y) + bb.y, 0.f);
        o.z = fmaxf(fmaf(w.z, inv, a.z) + bb.z, 0.f);
        o.w = fmaxf(fmaf(w.w, inv, a.w) + bb.w, 0.f);
        out4[(size_t)b * RPB * (EMB / 4) + i] = o;
    }
}

extern "C" void kernel_launch(void* const* d_in, const int* in_sizes, int n_in,
                              void* d_out, int out_size, void* d_ws, size_t ws_size,
                              hipStream_t stream) {
    const int E = in_sizes[0] / 2;
    const int* row = (const int*)d_in[0];
    const int* col = row + E;
    const float* user_weight = (const float*)d_in[1];
    const float* user_bias   = (const float*)d_in[2];
    const float* item_emb    = (const float*)d_in[3];
    float* out = (float*)d_out;
    float* item_out = out + (size_t)N_USERS * EMB;

    // Scratch in dead item half of d_out (~13.7 MB < 25.6 MB):
    unsigned* pairs  = (unsigned*)item_out;            // E u32 (12.8 MB)
    unsigned* deg    = pairs + E;                      // N u32
    float*    dis    = (float*)(deg + N_USERS);        // N f32
    unsigned* hist   = (unsigned*)(dis + N_USERS);     // NB*PAD u32 (32 KB)
    unsigned* cursor = hist + NB * PAD;                // NB*PAD u32 (32 KB)
    unsigned* base   = cursor + NB * PAD;              // NB+1 u32

    hipMemsetAsync(deg, 0, (size_t)N_USERS * 4, stream);
    hipMemsetAsync(hist, 0, (size_t)NB * PAD * 4, stream);

    count_hist_kernel<<<2048, 256, 0, stream>>>(row, E, deg, hist);
    dis_kernel<<<(N_USERS + 255) / 256, 256, 0, stream>>>(deg, dis, N_USERS);
    scan_hist_kernel<<<1, 512, 0, stream>>>(hist, base, cursor, NB);
    scatter_pairs_kernel<<<2048, 256, 0, stream>>>(row, col, cursor, pairs, E);

    aggregate_kernel<<<NB, 512, 0, stream>>>(base, dis, pairs,
                                             (const float4*)user_weight,
                                             (const float4*)user_bias,
                                             (float4*)out);

    // item passthrough LAST (overwrites scratch region)
    hipMemcpyAsync(item_out, item_emb, (size_t)in_sizes[3] * sizeof(float),
                   hipMemcpyDeviceToDevice, stream);
}

// Round 13
// 538.993 us; speedup vs baseline: 2.9045x; 2.9045x over previous
//
#include <hip/hip_runtime.h>

// GCN user tower: user_h = relu(D^-1/2 (A+I) D^-1/2 @ W + b), items passthrough.
// v4: hist -> scan -> LDS-staged partition (wave-cooperative chunk flush, no
// cross-XCD false sharing) -> per-bucket LDS counting sort (exact CSR, in
// place; also emits dis = rsqrt(deg+1)) -> v2's register-accumulating gather
// at full occupancy. Scratch lives in the dead item half of d_out.

constexpr int N_USERS = 100000;
constexpr int EMB = 64;
constexpr int RPB = 200;                 // rows per bucket
constexpr int NB = N_USERS / RPB;        // 500 buckets
constexpr int PAD = 16;                  // u32 stride: one 64B line per cursor
constexpr int DEPTH = 16;                // LDS slots per bucket in partition
constexpr int FT = 8;                    // flush threshold (chunk >= 32 B)
constexpr int PART_BLOCKS = 256;
constexpr int CAP = 10240;               // sort LDS capacity (mean 6400, sd 80)

// --- K1: bucket histogram, LDS-privatized ---
__global__ void hist_kernel(const int* __restrict__ row, int E,
                            unsigned* __restrict__ hist) {
    __shared__ unsigned h[NB];
    for (int i = threadIdx.x; i < NB; i += blockDim.x) h[i] = 0;
    __syncthreads();
    int stride = gridDim.x * blockDim.x;
    for (int e = blockIdx.x * blockDim.x + threadIdx.x; e < E; e += stride)
        atomicAdd(&h[row[e] / RPB], 1u);
    __syncthreads();
    for (int i = threadIdx.x; i < NB; i += blockDim.x)
        if (h[i]) atomicAdd(&hist[i], h[i]);
}

// --- K2: exclusive scan of 500 counts; init base, cursors, sentinel ---
__global__ void scan_kernel(const unsigned* __restrict__ hist,
                            unsigned* __restrict__ base,
                            unsigned* __restrict__ gcur,
                            unsigned* __restrict__ row_start, int E) {
    __shared__ unsigned tmp[512], orig[512];
    int t = threadIdx.x;
    unsigned v = (t < NB) ? hist[t] : 0u;
    tmp[t] = v; orig[t] = v;
    __syncthreads();
    for (int off = 1; off < 512; off <<= 1) {
        unsigned a = (t >= off) ? tmp[t - off] : 0u;
        __syncthreads();
        tmp[t] += a;
        __syncthreads();
    }
    if (t < NB) { unsigned ex = tmp[t] - orig[t]; base[t] = ex; gcur[t * PAD] = ex; }
    if (t == NB) base[NB] = (unsigned)E;
    if (t == NB + 1) row_start[N_USERS] = (unsigned)E;   // gather sentinel
}

// --- K3: LDS-staged partition into 500 bucket regions (packed pairs) ---
__global__ __launch_bounds__(256) void partition_kernel(
    const int* __restrict__ row, const int* __restrict__ col,
    unsigned* __restrict__ gcur, unsigned* __restrict__ pairs, int E) {
    __shared__ unsigned bins[NB * DEPTH];       // 32 KB
    __shared__ unsigned cnt[NB];
    __shared__ unsigned short work[NB];
    __shared__ unsigned nwork;
    const int tid = threadIdx.x;
    const int wave = tid >> 6, lane = tid & 63, nwaves = 256 / 64;
    for (int i = tid; i < NB; i += 256) cnt[i] = 0;
    __syncthreads();

    int per = (E + gridDim.x - 1) / gridDim.x;
    int s = blockIdx.x * per;
    int eEnd = min(E, s + per);

    for (int b0 = s; b0 < eEnd; b0 += 256) {
        if (tid == 0) nwork = 0;
        int e = b0 + tid;
        if (e < eEnd) {
            int r = row[e], c = col[e];
            int b = r / RPB;
            unsigned pair = ((unsigned)(r - b * RPB) << 17) | (unsigned)c;
            unsigned pos = atomicAdd(&cnt[b], 1u);
            if (pos < DEPTH) bins[b * DEPTH + pos] = pair;
            else pairs[atomicAdd(&gcur[b * PAD], 1u)] = pair;  // rare spill
        }
        __syncthreads();
        for (int i = tid; i < NB; i += 256) {
            unsigned n = cnt[i];
            if (n >= FT) { unsigned w = atomicAdd(&nwork, 1u); work[w] = (unsigned short)i; }
        }
        __syncthreads();
        for (unsigned w = wave; w < nwork; w += nwaves) {
            int b = work[w];
            unsigned n = min(cnt[b], (unsigned)DEPTH);
            unsigned gp = 0;
            if (lane == 0) gp = atomicAdd(&gcur[b * PAD], n);
            gp = __shfl(gp, 0, 64);
            if (lane < (int)n) pairs[gp + lane] = bins[b * DEPTH + lane];
            if (lane == 0) cnt[b] = 0;
        }
        __syncthreads();
    }
    // final flush of partial bins
    if (tid == 0) nwork = 0;
    __syncthreads();
    for (int i = tid; i < NB; i += 256) {
        unsigned n = cnt[i];
        if (n > 0) { unsigned w = atomicAdd(&nwork, 1u); work[w] = (unsigned short)i; }
    }
    __syncthreads();
    for (unsigned w = wave; w < nwork; w += nwaves) {
        int b = work[w];
        unsigned n = min(cnt[b], (unsigned)DEPTH);
        unsigned gp = 0;
        if (lane == 0) gp = atomicAdd(&gcur[b * PAD], n);
        gp = __shfl(gp, 0, 64);
        if (lane < (int)n) pairs[gp + lane] = bins[b * DEPTH + lane];
    }
}

// --- K4: per-bucket LDS counting sort (in place) + row_start + dis ---
__global__ __launch_bounds__(256) void sort_kernel(
    const unsigned* __restrict__ base, unsigned* __restrict__ pairs,
    unsigned* __restrict__ row_start, float* __restrict__ dis) {
    __shared__ unsigned lp[CAP];               // 40 KB
    __shared__ unsigned counts[RPB], cur[RPB], sc[256], orig[256];
    const int b = blockIdx.x, t = threadIdx.x;
    const unsigned s = base[b];
    const unsigned n = min(base[b + 1] - s, (unsigned)CAP);
    for (unsigned i = t; i < n; i += 256) lp[i] = pairs[s + i];
    for (int i = t; i < RPB; i += 256) counts[i] = 0;
    __syncthreads();
    for (unsigned i = t; i < n; i += 256) atomicAdd(&counts[lp[i] >> 17], 1u);
    __syncthreads();
    unsigned v = (t < RPB) ? counts[t] : 0u;
    sc[t] = v; orig[t] = v;
    __syncthreads();
    for (int off = 1; off < 256; off <<= 1) {
        unsigned a = (t >= off) ? sc[t - off] : 0u;
        __syncthreads();
        sc[t] += a;
        __syncthreads();
    }
    if (t < RPB) {
        unsigned ex = sc[t] - orig[t];
        row_start[b * RPB + t] = s + ex;
        cur[t] = ex;
        dis[b * RPB + t] = rsqrtf((float)(orig[t] + 1u));  // +1 self loop
    }
    __syncthreads();
    for (unsigned i = t; i < n; i += 256) {
        unsigned p = lp[i];
        unsigned pos = atomicAdd(&cur[p >> 17], 1u);
        pairs[s + pos] = p & 0x1FFFFu;                    // store col only
    }
}

// --- K5: register-accumulating gather + self loop + bias + relu ---
__global__ void gather_kernel(const unsigned* __restrict__ row_start,
                              const float* __restrict__ dis,
                              const unsigned* __restrict__ perm,
                              const float4* __restrict__ uw4,
                              const float4* __restrict__ bias4,
                              float4* __restrict__ out4) {
    int t = blockIdx.x * blockDim.x + threadIdx.x;
    int r = t >> 4;
    if (r >= N_USERS) return;
    int l = t & 15;
    unsigned s = row_start[r], e = row_start[r + 1];
    float dr = dis[r];
    float4 acc = make_float4(0.f, 0.f, 0.f, 0.f);
    for (unsigned k = s; k < e; ++k) {
        unsigned c = perm[k];
        float dc = dis[c];
        float4 w = uw4[(size_t)c * 16 + l];
        acc.x = fmaf(w.x, dc, acc.x);
        acc.y = fmaf(w.y, dc, acc.y);
        acc.z = fmaf(w.z, dc, acc.z);
        acc.w = fmaf(w.w, dc, acc.w);
    }
    float inv = dr * dr;  // 1/deg_total
    float4 ws = uw4[(size_t)r * 16 + l];
    float4 bb = bias4[l];
    float4 o;
    o.x = fmaxf(fmaf(acc.x, dr, fmaf(ws.x, inv, bb.x)), 0.f);
    o.y = fmaxf(fmaf(acc.y, dr, fmaf(ws.y, inv, bb.y)), 0.f);
    o.z = fmaxf(fmaf(acc.z, dr, fmaf(ws.z, inv, bb.z)), 0.f);
    o.w = fmaxf(fmaf(acc.w, dr, fmaf(ws.w, inv, bb.w)), 0.f);
    out4[t] = o;
}

extern "C" void kernel_launch(void* const* d_in, const int* in_sizes, int n_in,
                              void* d_out, int out_size, void* d_ws, size_t ws_size,
                              hipStream_t stream) {
    const int E = in_sizes[0] / 2;
    const int* row = (const int*)d_in[0];
    const int* col = row + E;
    const float* user_weight = (const float*)d_in[1];
    const float* user_bias   = (const float*)d_in[2];
    const float* item_emb    = (const float*)d_in[3];
    float* out = (float*)d_out;
    float* item_out = out + (size_t)N_USERS * EMB;

    // Scratch in dead item half of d_out (~13.7 MB < 25.6 MB):
    unsigned* pairs     = (unsigned*)item_out;            // E u32 (12.8 MB)
    unsigned* row_start = pairs + E;                      // N+1 u32
    float*    dis       = (float*)(row_start + N_USERS + 1); // N f32
    unsigned* hist      = (unsigned*)(dis + N_USERS);     // NB u32
    unsigned* gcur      = hist + NB;                      // NB*PAD u32 (32 KB)
    unsigned* base      = gcur + NB * PAD;                // NB+1 u32

    hipMemsetAsync(hist, 0, (size_t)NB * 4, stream);

    hist_kernel<<<512, 256, 0, stream>>>(row, E, hist);
    scan_kernel<<<1, 512, 0, stream>>>(hist, base, gcur, row_start, E);
    partition_kernel<<<PART_BLOCKS, 256, 0, stream>>>(row, col, gcur, pairs, E);
    sort_kernel<<<NB, 256, 0, stream>>>(base, pairs, row_start, dis);

    int gblocks = (N_USERS * 16 + 255) / 256;
    gather_kernel<<<gblocks, 256, 0, stream>>>(row_start, dis, pairs,
                                               (const float4*)user_weight,
                                               (const float4*)user_bias,
                                               (float4*)out);

    // item passthrough LAST (overwrites scratch region)
    hipMemcpyAsync(item_out, item_emb, (size_t)in_sizes[3] * sizeof(float),
                   hipMemcpyDeviceToDevice, stream);
}

// Round 15
// 365.565 us; speedup vs baseline: 4.2824x; 1.4744x over previous
//
#include <hip/hip_runtime.h>

// GCN user tower: user_h = relu(D^-1/2 (A+I) D^-1/2 @ W + b), items passthrough.
// v5: hist -> scan -> two-pass block-local reserve partition (one atomic
// reservation per (block,bucket), contiguous runs, no flush machinery) ->
// per-bucket LDS counting sort -> wave-per-row register gather (4-way edge
// ILP + shfl reduce). Scratch lives in the dead item half of d_out.

constexpr int N_USERS = 100000;
constexpr int EMB = 64;
constexpr int RPB = 200;                 // rows per bucket
constexpr int NB = N_USERS / RPB;        // 500 buckets
constexpr int PAD = 16;                  // u32 stride: one 64B line per cursor
constexpr int P2_BLOCKS = 1024;
constexpr int CAP = 10240;               // sort LDS capacity (mean 6400, sd 80)

// --- K1: bucket histogram, LDS-privatized ---
__global__ void hist_kernel(const int* __restrict__ row, int E,
                            unsigned* __restrict__ hist) {
    __shared__ unsigned h[NB];
    for (int i = threadIdx.x; i < NB; i += blockDim.x) h[i] = 0;
    __syncthreads();
    int stride = gridDim.x * blockDim.x;
    for (int e = blockIdx.x * blockDim.x + threadIdx.x; e < E; e += stride)
        atomicAdd(&h[row[e] / RPB], 1u);
    __syncthreads();
    for (int i = threadIdx.x; i < NB; i += blockDim.x)
        if (h[i]) atomicAdd(&hist[i], h[i]);
}

// --- K2: exclusive scan of 500 counts; init base, cursors, sentinel ---
__global__ void scan_kernel(const unsigned* __restrict__ hist,
                            unsigned* __restrict__ base,
                            unsigned* __restrict__ gcur,
                            unsigned* __restrict__ row_start, int E) {
    __shared__ unsigned tmp[512], orig[512];
    int t = threadIdx.x;
    unsigned v = (t < NB) ? hist[t] : 0u;
    tmp[t] = v; orig[t] = v;
    __syncthreads();
    for (int off = 1; off < 512; off <<= 1) {
        unsigned a = (t >= off) ? tmp[t - off] : 0u;
        __syncthreads();
        tmp[t] += a;
        __syncthreads();
    }
    if (t < NB) { unsigned ex = tmp[t] - orig[t]; base[t] = ex; gcur[t * PAD] = ex; }
    if (t == NB) base[NB] = (unsigned)E;
    if (t == NB + 1) row_start[N_USERS] = (unsigned)E;   // gather sentinel
}

// --- K3: two-pass partition. Pass 1: local hist + bulk reserve.
//         Pass 2: write pairs into the block's contiguous per-bucket runs. ---
__global__ __launch_bounds__(256) void partition2_kernel(
    const int* __restrict__ row, const int* __restrict__ col,
    unsigned* __restrict__ gcur, unsigned* __restrict__ pairs, int E) {
    __shared__ unsigned lcnt[NB];    // local count, then local cursor
    __shared__ unsigned lbase[NB];   // reserved global base per bucket
    const int tid = threadIdx.x;
    int per = (E + gridDim.x - 1) / gridDim.x;
    int s = blockIdx.x * per;
    int eEnd = min(E, s + per);

    for (int i = tid; i < NB; i += 256) lcnt[i] = 0;
    __syncthreads();
    for (int e = s + tid; e < eEnd; e += 256)
        atomicAdd(&lcnt[row[e] / RPB], 1u);
    __syncthreads();
    for (int i = tid; i < NB; i += 256) {
        unsigned n = lcnt[i];
        lbase[i] = n ? atomicAdd(&gcur[i * PAD], n) : 0u;
        lcnt[i] = 0;                  // reuse as local cursor
    }
    __syncthreads();
    for (int e = s + tid; e < eEnd; e += 256) {
        int r = row[e], c = col[e];
        int b = r / RPB;
        unsigned pos = lbase[b] + atomicAdd(&lcnt[b], 1u);
        pairs[pos] = ((unsigned)(r - b * RPB) << 17) | (unsigned)c;  // 8+17 bits
    }
}

// --- K4: per-bucket LDS counting sort (in place) + row_start + dis ---
__global__ __launch_bounds__(256) void sort_kernel(
    const unsigned* __restrict__ base, unsigned* __restrict__ pairs,
    unsigned* __restrict__ row_start, float* __restrict__ dis) {
    __shared__ unsigned lp[CAP];               // 40 KB
    __shared__ unsigned counts[RPB], cur[RPB], sc[256], orig[256];
    const int b = blockIdx.x, t = threadIdx.x;
    const unsigned s = base[b];
    const unsigned n = min(base[b + 1] - s, (unsigned)CAP);
    for (unsigned i = t; i < n; i += 256) lp[i] = pairs[s + i];
    for (int i = t; i < RPB; i += 256) counts[i] = 0;
    __syncthreads();
    for (unsigned i = t; i < n; i += 256) atomicAdd(&counts[lp[i] >> 17], 1u);
    __syncthreads();
    unsigned v = (t < RPB) ? counts[t] : 0u;
    sc[t] = v; orig[t] = v;
    __syncthreads();
    for (int off = 1; off < 256; off <<= 1) {
        unsigned a = (t >= off) ? sc[t - off] : 0u;
        __syncthreads();
        sc[t] += a;
        __syncthreads();
    }
    if (t < RPB) {
        unsigned ex = sc[t] - orig[t];
        row_start[b * RPB + t] = s + ex;
        cur[t] = ex;
        dis[b * RPB + t] = rsqrtf((float)(orig[t] + 1u));  // +1 self loop
    }
    __syncthreads();
    for (unsigned i = t; i < n; i += 256) {
        unsigned p = lp[i];
        unsigned pos = atomicAdd(&cur[p >> 17], 1u);
        pairs[s + pos] = p & 0x1FFFFu;                    // store col only
    }
}

// --- K5: wave-per-row gather, 4 edge-subgroups x 16 lanes, shfl reduce ---
__global__ void gather_kernel(const unsigned* __restrict__ row_start,
                              const float* __restrict__ dis,
                              const unsigned* __restrict__ perm,
                              const float4* __restrict__ uw4,
                              const float4* __restrict__ bias4,
                              float4* __restrict__ out4) {
    int r = (blockIdx.x * blockDim.x + threadIdx.x) >> 6;   // one wave per row
    if (r >= N_USERS) return;
    int lane = threadIdx.x & 63;
    int l = lane & 15;        // float4 slot (EMB/4 = 16)
    int sub = lane >> 4;      // edge subgroup 0..3
    unsigned s = row_start[r], e = row_start[r + 1];
    float4 acc = make_float4(0.f, 0.f, 0.f, 0.f);
    for (unsigned k = s + sub; k < e; k += 4) {
        unsigned c = perm[k];
        float dc = dis[c];
        float4 w = uw4[(size_t)c * 16 + l];
        acc.x = fmaf(w.x, dc, acc.x);
        acc.y = fmaf(w.y, dc, acc.y);
        acc.z = fmaf(w.z, dc, acc.z);
        acc.w = fmaf(w.w, dc, acc.w);
    }
    // butterfly reduce over the 4 subgroups (lane ^ 16, lane ^ 32)
    acc.x += __shfl_xor(acc.x, 16, 64);
    acc.y += __shfl_xor(acc.y, 16, 64);
    acc.z += __shfl_xor(acc.z, 16, 64);
    acc.w += __shfl_xor(acc.w, 16, 64);
    acc.x += __shfl_xor(acc.x, 32, 64);
    acc.y += __shfl_xor(acc.y, 32, 64);
    acc.z += __shfl_xor(acc.z, 32, 64);
    acc.w += __shfl_xor(acc.w, 32, 64);
    if (sub == 0) {
        float dr = dis[r];
        float inv = dr * dr;  // 1/deg_total
        float4 ws = uw4[(size_t)r * 16 + l];
        float4 bb = bias4[l];
        float4 o;
        o.x = fmaxf(fmaf(acc.x, dr, fmaf(ws.x, inv, bb.x)), 0.f);
        o.y = fmaxf(fmaf(acc.y, dr, fmaf(ws.y, inv, bb.y)), 0.f);
        o.z = fmaxf(fmaf(acc.z, dr, fmaf(ws.z, inv, bb.z)), 0.f);
        o.w = fmaxf(fmaf(acc.w, dr, fmaf(ws.w, inv, bb.w)), 0.f);
        out4[(size_t)r * 16 + l] = o;
    }
}

extern "C" void kernel_launch(void* const* d_in, const int* in_sizes, int n_in,
                              void* d_out, int out_size, void* d_ws, size_t ws_size,
                              hipStream_t stream) {
    const int E = in_sizes[0] / 2;
    const int* row = (const int*)d_in[0];
    const int* col = row + E;
    const float* user_weight = (const float*)d_in[1];
    const float* user_bias   = (const float*)d_in[2];
    const float* item_emb    = (const float*)d_in[3];
    float* out = (float*)d_out;
    float* item_out = out + (size_t)N_USERS * EMB;

    // Scratch in dead item half of d_out (~13.7 MB < 25.6 MB):
    unsigned* pairs     = (unsigned*)item_out;               // E u32 (12.8 MB)
    unsigned* row_start = pairs + E;                         // N+1 u32
    float*    dis       = (float*)(row_start + N_USERS + 1); // N f32
    unsigned* hist      = (unsigned*)(dis + N_USERS);        // NB u32
    unsigned* gcur      = hist + NB;                         // NB*PAD u32 (32 KB)
    unsigned* base      = gcur + NB * PAD;                   // NB+1 u32

    hipMemsetAsync(hist, 0, (size_t)NB * 4, stream);

    hist_kernel<<<512, 256, 0, stream>>>(row, E, hist);
    scan_kernel<<<1, 512, 0, stream>>>(hist, base, gcur, row_start, E);
    partition2_kernel<<<P2_BLOCKS, 256, 0, stream>>>(row, col, gcur, pairs, E);
    sort_kernel<<<NB, 256, 0, stream>>>(base, pairs, row_start, dis);

    int gblocks = (N_USERS * 64 + 255) / 256;   // one wave (64 thr) per row
    gather_kernel<<<gblocks, 256, 0, stream>>>(row_start, dis, pairs,
                                               (const float4*)user_weight,
                                               (const float4*)user_bias,
                                               (float4*)out);

    // item passthrough LAST (overwrites scratch region)
    hipMemcpyAsync(item_out, item_emb, (size_t)in_sizes[3] * sizeof(float),
                   hipMemcpyDeviceToDevice, stream);
}